// Round 2
// baseline (1143.561 us; speedup 1.0000x reference)
//
#include <hip/hip_runtime.h>

#define B_   8
#define C_   512
#define HW_  2304
#define BM   128
#define BN   128
#define BK   64
#define SP   72   // padded LDS row stride (bf16 elems): quad frag reads -> 2-way (free)

typedef __bf16 bf16x8 __attribute__((ext_vector_type(8)));
typedef float  f32x4  __attribute__((ext_vector_type(4)));

__device__ __forceinline__ unsigned short f2bf(float f) {
  unsigned int u = __float_as_uint(f);
  u += 0x7FFF + ((u >> 16) & 1);   // round-to-nearest-even
  return (unsigned short)(u >> 16);
}

// key fp32 [b][c][n] -> keyT bf16 [b][n][c]
__global__ void transpose_key(const float* __restrict__ key,
                              unsigned short* __restrict__ keyT) {
  __shared__ float tile[32][33];
  int b  = blockIdx.z;
  int n0 = blockIdx.x * 32;
  int c0 = blockIdx.y * 32;
  int tx = threadIdx.x;  // 0..31
  int ty = threadIdx.y;  // 0..7
#pragma unroll
  for (int i = 0; i < 4; i++) {
    int c = c0 + ty + i * 8;
    tile[ty + i * 8][tx] = key[(size_t)b * C_ * HW_ + (size_t)c * HW_ + n0 + tx];
  }
  __syncthreads();
#pragma unroll
  for (int i = 0; i < 4; i++) {
    int n = n0 + ty + i * 8;
    keyT[(size_t)b * HW_ * C_ + (size_t)n * C_ + c0 + tx] = f2bf(tile[tx][ty + i * 8]);
  }
}

// 4 fine banks fp32 [b][m][c] -> bf16 same layout, stacked [g][b][m][c]
__global__ void convert_banks(const float* __restrict__ b0, const float* __restrict__ b1,
                              const float* __restrict__ b2, const float* __restrict__ b3,
                              unsigned short* __restrict__ out) {
  const size_t per = (size_t)B_ * HW_ * C_;
  int g = blockIdx.y;
  const float* src = (g == 0) ? b0 : (g == 1) ? b1 : (g == 2) ? b2 : b3;
  size_t i = ((size_t)blockIdx.x * blockDim.x + threadIdx.x) * 4;
  float4 v = *(const float4*)(src + i);
  ushort4 o;
  o.x = f2bf(v.x); o.y = f2bf(v.y); o.z = f2bf(v.z); o.w = f2bf(v.w);
  *(ushort4*)(out + g * per + i) = o;
}

// 6 coarse dots: out[b][4+j][n] = sum_c coarse_j[b][c] * key[b][c][n]
__global__ void coarse_kernel(const float* __restrict__ key,
                              const float* __restrict__ c0, const float* __restrict__ c1,
                              const float* __restrict__ c2, const float* __restrict__ c3,
                              const float* __restrict__ c4, const float* __restrict__ c5,
                              float* __restrict__ out) {
  int b = blockIdx.y;
  int n = blockIdx.x * 256 + threadIdx.x;
  const float* kb = key + (size_t)b * C_ * HW_;
  float s0 = 0.f, s1 = 0.f, s2 = 0.f, s3 = 0.f, s4 = 0.f, s5 = 0.f;
  for (int c = 0; c < C_; c++) {
    float kv = kb[(size_t)c * HW_ + n];
    s0 += c0[b * C_ + c] * kv;
    s1 += c1[b * C_ + c] * kv;
    s2 += c2[b * C_ + c] * kv;
    s3 += c3[b * C_ + c] * kv;
    s4 += c4[b * C_ + c] * kv;
    s5 += c5[b * C_ + c] * kv;
  }
  size_t base = ((size_t)b * 10) * HW_ + n;
  out[base + 4 * HW_] = s0;
  out[base + 5 * HW_] = s1;
  out[base + 6 * HW_] = s2;
  out[base + 7 * HW_] = s3;
  out[base + 8 * HW_] = s4;
  out[base + 9 * HW_] = s5;
}

// Fine scores: per (n-tile, bank, batch) block, loop all m, GEMM via MFMA,
// fused mask-mul + column max. out[b][g][n].
__global__ __launch_bounds__(256) void fine_kernel(
    const unsigned short* __restrict__ keyT,   // bf16 [b][n][c]
    const unsigned short* __restrict__ banks,  // bf16 [g][b][m][c]
    const float* __restrict__ sds,             // fp32 [b][m][n]
    float* __restrict__ out) {
  int nt = blockIdx.x;  // 0..17
  int g  = blockIdx.y;  // 0..3
  int b  = blockIdx.z;  // 0..7
  int n0 = nt * BN;

  __shared__ unsigned short Al[BM * SP];
  __shared__ unsigned short Bl[BN * SP];
  __shared__ float red[2 * BN];

  int t    = threadIdx.x;
  int wave = t >> 6;
  int lane = t & 63;
  int quad = lane >> 4;
  int l15  = lane & 15;
  int wm   = (wave & 1) * 64;
  int wn   = (wave >> 1) * 64;

  const unsigned short* bank = banks + ((size_t)g * B_ + b) * (size_t)HW_ * C_;
  const unsigned short* keyb = keyT + (size_t)b * HW_ * C_;
  const float* maskb = sds + (size_t)b * HW_ * HW_;
  const bool masked = (g >= 2);

  float runmax[4];
#pragma unroll
  for (int i = 0; i < 4; i++) runmax[i] = -3.4e38f;

  for (int mt = 0; mt < HW_ / BM; mt++) {
    int m0 = mt * BM;
    f32x4 acc[4][4];
#pragma unroll
    for (int i = 0; i < 4; i++)
#pragma unroll
      for (int j = 0; j < 4; j++)
#pragma unroll
        for (int e = 0; e < 4; e++) acc[i][j][e] = 0.0f;

    for (int kc = 0; kc < C_ / BK; kc++) {
      __syncthreads();
      // stage A (bank rows m0..m0+127) and B (keyT rows n0..n0+127), 64 k each
#pragma unroll
      for (int i = 0; i < 4; i++) {
        int ch  = t + i * 256;
        int row = ch >> 3;
        int sub = ch & 7;
        uint4 va = *(const uint4*)(bank + (size_t)(m0 + row) * C_ + kc * BK + sub * 8);
        *(uint4*)(&Al[row * SP + sub * 8]) = va;
        uint4 vb = *(const uint4*)(keyb + (size_t)(n0 + row) * C_ + kc * BK + sub * 8);
        *(uint4*)(&Bl[row * SP + sub * 8]) = vb;
      }
      __syncthreads();
#pragma unroll
      for (int k0 = 0; k0 < BK; k0 += 32) {
        bf16x8 af[4], bfr[4];
#pragma unroll
        for (int ms = 0; ms < 4; ms++)
          af[ms] = *(const bf16x8*)(&Al[(wm + ms * 16 + l15) * SP + k0 + quad * 8]);
#pragma unroll
        for (int ns = 0; ns < 4; ns++)
          bfr[ns] = *(const bf16x8*)(&Bl[(wn + ns * 16 + l15) * SP + k0 + quad * 8]);
#pragma unroll
        for (int ms = 0; ms < 4; ms++)
#pragma unroll
          for (int ns = 0; ns < 4; ns++)
            acc[ms][ns] = __builtin_amdgcn_mfma_f32_16x16x32_bf16(
                af[ms], bfr[ns], acc[ms][ns], 0, 0, 0);
      }
    }

    // epilogue: lane holds S[m0+wm+ms*16+quad*4+r][n0+wn+ns*16+l15]
#pragma unroll
    for (int ms = 0; ms < 4; ms++) {
#pragma unroll
      for (int ns = 0; ns < 4; ns++) {
        int n = n0 + wn + ns * 16 + l15;
#pragma unroll
        for (int r = 0; r < 4; r++) {
          int m = m0 + wm + ms * 16 + quad * 4 + r;
          float s = acc[ms][ns][r];
          if (masked) s *= maskb[(size_t)m * HW_ + n];
          runmax[ns] = fmaxf(runmax[ns], s);
        }
      }
    }
  }

  // reduce across quads (same column, different m rows)
#pragma unroll
  for (int ns = 0; ns < 4; ns++) {
    float v = runmax[ns];
    v = fmaxf(v, __shfl_xor(v, 16, 64));
    v = fmaxf(v, __shfl_xor(v, 32, 64));
    runmax[ns] = v;
  }
  if (lane < 16) {
#pragma unroll
    for (int ns = 0; ns < 4; ns++)
      red[(wave & 1) * BN + wn + ns * 16 + l15] = runmax[ns];
  }
  __syncthreads();
  if (t < BN) {
    float v = fmaxf(red[t], red[BN + t]);
    out[((size_t)b * 10 + g) * HW_ + n0 + t] = v;
  }
}

extern "C" void kernel_launch(void* const* d_in, const int* in_sizes, int n_in,
                              void* d_out, int out_size, void* d_ws, size_t ws_size,
                              hipStream_t stream) {
  const float* key  = (const float*)d_in[0];
  const float* sds  = (const float*)d_in[1];
  const float* gbg  = (const float*)d_in[2];
  const float* gfg  = (const float*)d_in[3];
  const float* lbg  = (const float*)d_in[4];
  const float* lfg  = (const float*)d_in[5];
  const float* obg  = (const float*)d_in[6];
  const float* ofg  = (const float*)d_in[7];
  const float* sbg  = (const float*)d_in[8];
  const float* sfg  = (const float*)d_in[9];
  const float* lobg = (const float*)d_in[10];
  const float* lofg = (const float*)d_in[11];
  float* out = (float*)d_out;

  unsigned short* keyT  = (unsigned short*)d_ws;                 // 18.9 MB
  unsigned short* banks = keyT + (size_t)B_ * HW_ * C_;          // +75.5 MB (ws total ~94 MB)

  transpose_key<<<dim3(HW_ / 32, C_ / 32, B_), dim3(32, 8), 0, stream>>>(key, keyT);
  convert_banks<<<dim3((B_ * HW_ * C_) / (4 * 256), 4), 256, 0, stream>>>(gbg, gfg, lbg, lfg, banks);
  coarse_kernel<<<dim3(HW_ / 256, B_), 256, 0, stream>>>(key, obg, ofg, sbg, sfg, lobg, lofg, out);
  fine_kernel<<<dim3(HW_ / BN, 4, B_), 256, 0, stream>>>(keyT, banks, sds, out);
}

// Round 3
// 829.390 us; speedup vs baseline: 1.3788x; 1.3788x over previous
//
#include <hip/hip_runtime.h>

#define B_   8
#define C_   512
#define HW_  2304
#define BM   128
#define BN   128
#define BK   64
#define NT_  (HW_ / BN)      // 18
#define MT_PER_BLOCK 3
#define MCHUNKS 6            // 18 m-tiles / 3
#define CCH  8               // coarse c-chunks

typedef __bf16 bf16x8 __attribute__((ext_vector_type(8)));
typedef float  f32x4  __attribute__((ext_vector_type(4)));

__device__ __forceinline__ unsigned short f2bf(float f) {
  unsigned int u = __float_as_uint(f);
  u += 0x7FFF + ((u >> 16) & 1);   // round-to-nearest-even
  return (unsigned short)(u >> 16);
}

__device__ __forceinline__ void gload_lds16(const void* g, void* l) {
  __builtin_amdgcn_global_load_lds(
      (const __attribute__((address_space(1))) unsigned int*)g,
      (__attribute__((address_space(3))) unsigned int*)l, 16, 0, 0);
}

// key fp32 [b][c][n] -> keyT bf16 [b][n][c]
__global__ void transpose_key(const float* __restrict__ key,
                              unsigned short* __restrict__ keyT) {
  __shared__ float tile[32][33];
  int b  = blockIdx.z;
  int n0 = blockIdx.x * 32;
  int c0 = blockIdx.y * 32;
  int tx = threadIdx.x;  // 0..31
  int ty = threadIdx.y;  // 0..7
#pragma unroll
  for (int i = 0; i < 4; i++) {
    int c = c0 + ty + i * 8;
    tile[ty + i * 8][tx] = key[(size_t)b * C_ * HW_ + (size_t)c * HW_ + n0 + tx];
  }
  __syncthreads();
#pragma unroll
  for (int i = 0; i < 4; i++) {
    int n = n0 + ty + i * 8;
    keyT[(size_t)b * HW_ * C_ + (size_t)n * C_ + c0 + tx] = f2bf(tile[tx][ty + i * 8]);
  }
}

// 4 fine banks fp32 [b][m][c] -> bf16 stacked [g][b][m][c]
__global__ void convert_banks(const float* __restrict__ b0, const float* __restrict__ b1,
                              const float* __restrict__ b2, const float* __restrict__ b3,
                              unsigned short* __restrict__ out) {
  const size_t per = (size_t)B_ * HW_ * C_;
  int g = blockIdx.y;
  const float* src = (g == 0) ? b0 : (g == 1) ? b1 : (g == 2) ? b2 : b3;
  size_t i = ((size_t)blockIdx.x * blockDim.x + threadIdx.x) * 4;
  float4 v = *(const float4*)(src + i);
  ushort4 o;
  o.x = f2bf(v.x); o.y = f2bf(v.y); o.z = f2bf(v.z); o.w = f2bf(v.w);
  *(ushort4*)(out + g * per + i) = o;
}

// coarse partial dots over a 64-c chunk: part[cc][b][j][n]
__global__ void coarse_partial(const float* __restrict__ key,
                               const float* __restrict__ c0, const float* __restrict__ c1,
                               const float* __restrict__ c2, const float* __restrict__ c3,
                               const float* __restrict__ c4, const float* __restrict__ c5,
                               float* __restrict__ part) {
  int b  = blockIdx.y;
  int cc = blockIdx.z;
  int n  = blockIdx.x * 256 + threadIdx.x;
  const float* kb = key + (size_t)b * C_ * HW_;
  float s0 = 0.f, s1 = 0.f, s2 = 0.f, s3 = 0.f, s4 = 0.f, s5 = 0.f;
  for (int c = cc * 64; c < cc * 64 + 64; c++) {
    float kv = kb[(size_t)c * HW_ + n];
    s0 += c0[b * C_ + c] * kv;
    s1 += c1[b * C_ + c] * kv;
    s2 += c2[b * C_ + c] * kv;
    s3 += c3[b * C_ + c] * kv;
    s4 += c4[b * C_ + c] * kv;
    s5 += c5[b * C_ + c] * kv;
  }
  size_t base = (((size_t)cc * B_ + b) * 6) * HW_ + n;
  part[base + 0 * HW_] = s0;
  part[base + 1 * HW_] = s1;
  part[base + 2 * HW_] = s2;
  part[base + 3 * HW_] = s3;
  part[base + 4 * HW_] = s4;
  part[base + 5 * HW_] = s5;
}

// sum coarse partials -> out channels 4..9
__global__ void coarse_combine(const float* __restrict__ part, float* __restrict__ out) {
  int i = blockIdx.x * 256 + threadIdx.x;   // over B_*6*HW_
  if (i >= B_ * 6 * HW_) return;
  int n = i % HW_;
  int j = (i / HW_) % 6;
  int b = i / (HW_ * 6);
  float s = 0.f;
#pragma unroll
  for (int cc = 0; cc < CCH; cc++)
    s += part[(((size_t)cc * B_ + b) * 6 + j) * HW_ + n];
  out[((size_t)b * 10 + 4 + j) * HW_ + n] = s;
}

// Fine scores, m-split: block handles 3 m-tiles for one (nt, g, b); writes
// partial column max to pmax[mc][b][g][n].
__global__ __launch_bounds__(256, 4) void fine_kernel(
    const unsigned short* __restrict__ keyT,   // bf16 [b][n][c]
    const unsigned short* __restrict__ banks,  // bf16 [g][b][m][c]
    const float* __restrict__ sds,             // fp32 [b][m][n]
    float* __restrict__ pmax) {
  int nt = blockIdx.x % NT_;
  int mc = blockIdx.x / NT_;   // 0..5
  int g  = blockIdx.y;
  int b  = blockIdx.z;
  int n0 = nt * BN;

  __shared__ __align__(16) unsigned short Al[BM * 64];  // 16 KB, XOR-swizzled
  __shared__ __align__(16) unsigned short Bl[BN * 64];  // 16 KB
  __shared__ float red[2 * BN];

  int t    = threadIdx.x;
  int wave = t >> 6;
  int lane = t & 63;
  int quad = lane >> 4;
  int l15  = lane & 15;
  int wm   = (wave & 1) * 64;
  int wn   = (wave >> 1) * 64;

  // staging: wave stages rows [wave*32, wave*32+32); call j covers 8 rows.
  // lane -> row = base+ (lane>>3), lds slot s = lane&7, global sub = s ^ (row&7)
  int srow = lane >> 3;               // 0..7
  int ssub = (lane & 7) ^ srow;       // swizzle inverse on global side
  // fragment-read swizzled k offsets (elements): slot = (k0/8+quad) ^ (l15&7)
  int l7  = l15 & 7;
  int sw0 = ((quad) ^ l7) * 8;        // k0 = 0
  int sw1 = ((quad + 4) ^ l7) * 8;    // k0 = 32

  const unsigned short* bank = banks + ((size_t)g * B_ + b) * (size_t)HW_ * C_;
  const unsigned short* keyb = keyT + (size_t)b * HW_ * C_;
  const float* maskb = sds + (size_t)b * HW_ * HW_;
  const bool masked = (g >= 2);

  float runmax[4];
#pragma unroll
  for (int i = 0; i < 4; i++) runmax[i] = -3.4e38f;

  for (int mi = 0; mi < MT_PER_BLOCK; mi++) {
    int m0 = (mc * MT_PER_BLOCK + mi) * BM;
    f32x4 acc[4][4];
#pragma unroll
    for (int i = 0; i < 4; i++)
#pragma unroll
      for (int j = 0; j < 4; j++)
#pragma unroll
        for (int e = 0; e < 4; e++) acc[i][j][e] = 0.0f;

    for (int kc = 0; kc < C_ / BK; kc++) {
      __syncthreads();   // prior round's frag reads done before overwrite
#pragma unroll
      for (int j = 0; j < 4; j++) {
        int rbase = wave * 32 + j * 8;
        int row   = rbase + srow;
        gload_lds16(bank + (size_t)(m0 + row) * C_ + kc * BK + ssub * 8,
                    &Al[rbase * 64]);
        gload_lds16(keyb + (size_t)(n0 + row) * C_ + kc * BK + ssub * 8,
                    &Bl[rbase * 64]);
      }
      __syncthreads();   // drains vmcnt (global_load_lds) before use
#pragma unroll
      for (int k0 = 0; k0 < BK; k0 += 32) {
        int sw = (k0 == 0) ? sw0 : sw1;
        bf16x8 af[4], bfr[4];
#pragma unroll
        for (int ms = 0; ms < 4; ms++)
          af[ms] = *(const bf16x8*)(&Al[(wm + ms * 16 + l15) * 64 + sw]);
#pragma unroll
        for (int ns = 0; ns < 4; ns++)
          bfr[ns] = *(const bf16x8*)(&Bl[(wn + ns * 16 + l15) * 64 + sw]);
#pragma unroll
        for (int ms = 0; ms < 4; ms++)
#pragma unroll
          for (int ns = 0; ns < 4; ns++)
            acc[ms][ns] = __builtin_amdgcn_mfma_f32_16x16x32_bf16(
                af[ms], bfr[ns], acc[ms][ns], 0, 0, 0);
      }
    }

    // epilogue: lane holds S[m0+wm+ms*16+quad*4+r][n0+wn+ns*16+l15]
#pragma unroll
    for (int ms = 0; ms < 4; ms++) {
#pragma unroll
      for (int ns = 0; ns < 4; ns++) {
        int n = n0 + wn + ns * 16 + l15;
#pragma unroll
        for (int r = 0; r < 4; r++) {
          int m = m0 + wm + ms * 16 + quad * 4 + r;
          float s = acc[ms][ns][r];
          if (masked) s *= maskb[(size_t)m * HW_ + n];
          runmax[ns] = fmaxf(runmax[ns], s);
        }
      }
    }
  }

  // reduce across quads (same column, different m rows)
#pragma unroll
  for (int ns = 0; ns < 4; ns++) {
    float v = runmax[ns];
    v = fmaxf(v, __shfl_xor(v, 16, 64));
    v = fmaxf(v, __shfl_xor(v, 32, 64));
    runmax[ns] = v;
  }
  if (lane < 16) {
#pragma unroll
    for (int ns = 0; ns < 4; ns++)
      red[(wave & 1) * BN + wn + ns * 16 + l15] = runmax[ns];
  }
  __syncthreads();
  if (t < BN) {
    float v = fmaxf(red[t], red[BN + t]);
    pmax[(((size_t)mc * B_ + b) * 4 + g) * HW_ + n0 + t] = v;
  }
}

// max over m-chunks -> out channels 0..3
__global__ void fine_combine(const float* __restrict__ pmax, float* __restrict__ out) {
  int i = blockIdx.x * 256 + threadIdx.x;   // over B_*4*HW_
  if (i >= B_ * 4 * HW_) return;
  int n = i % HW_;
  int g = (i / HW_) % 4;
  int b = i / (HW_ * 4);
  float v = -3.4e38f;
#pragma unroll
  for (int mc = 0; mc < MCHUNKS; mc++)
    v = fmaxf(v, pmax[(((size_t)mc * B_ + b) * 4 + g) * HW_ + n]);
  out[((size_t)b * 10 + g) * HW_ + n] = v;
}

extern "C" void kernel_launch(void* const* d_in, const int* in_sizes, int n_in,
                              void* d_out, int out_size, void* d_ws, size_t ws_size,
                              hipStream_t stream) {
  const float* key  = (const float*)d_in[0];
  const float* sds  = (const float*)d_in[1];
  const float* gbg  = (const float*)d_in[2];
  const float* gfg  = (const float*)d_in[3];
  const float* lbg  = (const float*)d_in[4];
  const float* lfg  = (const float*)d_in[5];
  const float* obg  = (const float*)d_in[6];
  const float* ofg  = (const float*)d_in[7];
  const float* sbg  = (const float*)d_in[8];
  const float* sfg  = (const float*)d_in[9];
  const float* lobg = (const float*)d_in[10];
  const float* lofg = (const float*)d_in[11];
  float* out = (float*)d_out;

  unsigned short* keyT  = (unsigned short*)d_ws;               // 18.9 MB
  unsigned short* banks = keyT + (size_t)B_ * HW_ * C_;        // +75.5 MB
  float* pmax  = (float*)(banks + (size_t)4 * B_ * HW_ * C_);  // +1.77 MB
  float* cpart = pmax + (size_t)MCHUNKS * B_ * 4 * HW_;        // +3.54 MB (~99.7 MB total)

  transpose_key<<<dim3(HW_ / 32, C_ / 32, B_), dim3(32, 8), 0, stream>>>(key, keyT);
  convert_banks<<<dim3((B_ * HW_ * C_) / (4 * 256), 4), 256, 0, stream>>>(gbg, gfg, lbg, lfg, banks);
  coarse_partial<<<dim3(HW_ / 256, B_, CCH), 256, 0, stream>>>(key, obg, ofg, sbg, sfg, lobg, lofg, cpart);
  coarse_combine<<<(B_ * 6 * HW_ + 255) / 256, 256, 0, stream>>>(cpart, out);
  fine_kernel<<<dim3(NT_ * MCHUNKS, 4, B_), 256, 0, stream>>>(keyT, banks, sds, pmax);
  fine_combine<<<(B_ * 4 * HW_ + 255) / 256, 256, 0, stream>>>(pmax, out);
}

// Round 4
// 725.709 us; speedup vs baseline: 1.5758x; 1.1429x over previous
//
#include <hip/hip_runtime.h>

#define B_   8
#define C_   512
#define HW_  2304
#define BM   128
#define BN   128
#define BK   64
#define NT_  (HW_ / BN)      // 18
#define MT_PER_BLOCK 3
#define MCHUNKS 6            // 18 m-tiles / 3

typedef __bf16 bf16x8 __attribute__((ext_vector_type(8)));
typedef float  f32x4  __attribute__((ext_vector_type(4)));

__device__ __forceinline__ unsigned short f2bf(float f) {
  unsigned int u = __float_as_uint(f);
  u += 0x7FFF + ((u >> 16) & 1);   // round-to-nearest-even
  return (unsigned short)(u >> 16);
}

__device__ __forceinline__ void gload_lds16(const void* g, void* l) {
  __builtin_amdgcn_global_load_lds(
      (const __attribute__((address_space(1))) unsigned int*)g,
      (__attribute__((address_space(3))) unsigned int*)l, 16, 0, 0);
}

__global__ void zero_out(float* __restrict__ out, int n) {
  int i = blockIdx.x * 256 + threadIdx.x;
  if (i < n) out[i] = 0.0f;
}

// Fused: key fp32 [b][c][n] -> keyT bf16 [b][n][c], plus coarse partial dots
// (fp32, atomicAdd into pre-zeroed out channels 4..9).
__global__ void transpose_coarse(const float* __restrict__ key,
                                 const float* __restrict__ v0, const float* __restrict__ v1,
                                 const float* __restrict__ v2, const float* __restrict__ v3,
                                 const float* __restrict__ v4, const float* __restrict__ v5,
                                 unsigned short* __restrict__ keyT,
                                 float* __restrict__ out) {
  __shared__ float tile[32][33];
  __shared__ float red2[6][8][32];
  int b  = blockIdx.z;
  int n0 = blockIdx.x * 32;
  int c0 = blockIdx.y * 32;
  int tx = threadIdx.x;  // 0..31
  int ty = threadIdx.y;  // 0..7
#pragma unroll
  for (int i = 0; i < 4; i++) {
    int c = c0 + ty + i * 8;
    tile[ty + i * 8][tx] = key[(size_t)b * C_ * HW_ + (size_t)c * HW_ + n0 + tx];
  }
  __syncthreads();
#pragma unroll
  for (int i = 0; i < 4; i++) {
    int n = n0 + ty + i * 8;
    keyT[(size_t)b * HW_ * C_ + (size_t)n * C_ + c0 + tx] = f2bf(tile[tx][ty + i * 8]);
  }
  // coarse partials: thread covers n = n0+tx, c-range = c0 + ty*4 .. +4
  float s[6] = {0.f, 0.f, 0.f, 0.f, 0.f, 0.f};
#pragma unroll
  for (int i = 0; i < 4; i++) {
    int cr = ty * 4 + i;
    int c  = c0 + cr;
    float kv = tile[cr][tx];
    s[0] += v0[b * C_ + c] * kv;
    s[1] += v1[b * C_ + c] * kv;
    s[2] += v2[b * C_ + c] * kv;
    s[3] += v3[b * C_ + c] * kv;
    s[4] += v4[b * C_ + c] * kv;
    s[5] += v5[b * C_ + c] * kv;
  }
#pragma unroll
  for (int j = 0; j < 6; j++) red2[j][ty][tx] = s[j];
  __syncthreads();
  if (ty < 6) {
    float a = 0.f;
#pragma unroll
    for (int k = 0; k < 8; k++) a += red2[ty][k][tx];
    atomicAdd(&out[((size_t)b * 10 + 4 + ty) * HW_ + n0 + tx], a);
  }
}

// 4 fine banks fp32 [b][m][c] -> bf16 stacked [g][b][m][c]
__global__ void convert_banks(const float* __restrict__ b0, const float* __restrict__ b1,
                              const float* __restrict__ b2, const float* __restrict__ b3,
                              unsigned short* __restrict__ out) {
  const size_t per = (size_t)B_ * HW_ * C_;
  int g = blockIdx.y;
  const float* src = (g == 0) ? b0 : (g == 1) ? b1 : (g == 2) ? b2 : b3;
  size_t i = ((size_t)blockIdx.x * blockDim.x + threadIdx.x) * 4;
  float4 v = *(const float4*)(src + i);
  ushort4 o;
  o.x = f2bf(v.x); o.y = f2bf(v.y); o.z = f2bf(v.z); o.w = f2bf(v.w);
  *(ushort4*)(out + g * per + i) = o;
}

// Fine scores, bank-paired: block handles banks {2gp, 2gp+1} (they share the
// B tile and, for gp==1, the mask) for 3 m-tiles of one (nt, b).
// Writes partial column max to pmax[mc][b][g][n].
__global__ __launch_bounds__(256, 3) void fine_kernel(
    const unsigned short* __restrict__ keyT,   // bf16 [b][n][c]
    const unsigned short* __restrict__ banks,  // bf16 [g][b][m][c]
    const float* __restrict__ sds,             // fp32 [b][m][n]
    float* __restrict__ pmax) {
  int nt = blockIdx.x % NT_;
  int mc = blockIdx.x / NT_;   // 0..5
  int gp = blockIdx.y;         // 0: banks 0,1 (unmasked)  1: banks 2,3 (masked)
  int b  = blockIdx.z;
  int n0 = nt * BN;

  __shared__ __align__(16) unsigned short A0[BM * 64];  // 16 KB, XOR-swizzled
  __shared__ __align__(16) unsigned short A1[BM * 64];
  __shared__ __align__(16) unsigned short Bl[BN * 64];
  __shared__ float red[4 * BN];

  int t    = threadIdx.x;
  int wave = t >> 6;
  int lane = t & 63;
  int quad = lane >> 4;
  int l15  = lane & 15;
  int wm   = (wave & 1) * 64;
  int wn   = (wave >> 1) * 64;

  // staging swizzle: lds row = rbase + (lane>>3), global k-sub = (lane&7)^(row&7)
  int srow = lane >> 3;
  int ssub = (lane & 7) ^ srow;
  // fragment-read swizzled k offsets: slot = (k0/8 + quad) ^ (l15&7)
  int l7  = l15 & 7;
  int sw0 = ((quad) ^ l7) * 8;
  int sw1 = ((quad + 4) ^ l7) * 8;

  const unsigned short* bank0 = banks + ((size_t)(2 * gp) * B_ + b) * (size_t)HW_ * C_;
  const unsigned short* bank1 = banks + ((size_t)(2 * gp + 1) * B_ + b) * (size_t)HW_ * C_;
  const unsigned short* keyb  = keyT + (size_t)b * HW_ * C_;
  const float* maskb = sds + (size_t)b * HW_ * HW_;
  const bool masked = (gp == 1);

  float rm0[4], rm1[4];
#pragma unroll
  for (int i = 0; i < 4; i++) { rm0[i] = -3.4e38f; rm1[i] = -3.4e38f; }

  for (int mi = 0; mi < MT_PER_BLOCK; mi++) {
    int m0 = (mc * MT_PER_BLOCK + mi) * BM;
    f32x4 acc0[4][4], acc1[4][4];
#pragma unroll
    for (int i = 0; i < 4; i++)
#pragma unroll
      for (int j = 0; j < 4; j++)
#pragma unroll
        for (int e = 0; e < 4; e++) { acc0[i][j][e] = 0.0f; acc1[i][j][e] = 0.0f; }

    for (int kc = 0; kc < C_ / BK; kc++) {
      __syncthreads();   // prior round's frag reads done before overwrite
#pragma unroll
      for (int j = 0; j < 4; j++) {
        int rbase = wave * 32 + j * 8;
        int row   = rbase + srow;
        size_t goff = (size_t)row * C_ + kc * BK + ssub * 8;
        gload_lds16(bank0 + (size_t)m0 * C_ + goff, &A0[rbase * 64]);
        gload_lds16(bank1 + (size_t)m0 * C_ + goff, &A1[rbase * 64]);
        gload_lds16(keyb  + (size_t)n0 * C_ + goff, &Bl[rbase * 64]);
      }
      __syncthreads();   // drains vmcnt before use
#pragma unroll
      for (int k0 = 0; k0 < BK; k0 += 32) {
        int sw = (k0 == 0) ? sw0 : sw1;
        bf16x8 a0[4], a1[4], bb[4];
#pragma unroll
        for (int ms = 0; ms < 4; ms++) {
          a0[ms] = *(const bf16x8*)(&A0[(wm + ms * 16 + l15) * 64 + sw]);
          a1[ms] = *(const bf16x8*)(&A1[(wm + ms * 16 + l15) * 64 + sw]);
        }
#pragma unroll
        for (int ns = 0; ns < 4; ns++)
          bb[ns] = *(const bf16x8*)(&Bl[(wn + ns * 16 + l15) * 64 + sw]);
#pragma unroll
        for (int ms = 0; ms < 4; ms++)
#pragma unroll
          for (int ns = 0; ns < 4; ns++) {
            acc0[ms][ns] = __builtin_amdgcn_mfma_f32_16x16x32_bf16(
                a0[ms], bb[ns], acc0[ms][ns], 0, 0, 0);
            acc1[ms][ns] = __builtin_amdgcn_mfma_f32_16x16x32_bf16(
                a1[ms], bb[ns], acc1[ms][ns], 0, 0, 0);
          }
      }
    }

    // epilogue: lane holds S[m0+wm+ms*16+quad*4+r][n0+wn+ns*16+l15]
#pragma unroll
    for (int ms = 0; ms < 4; ms++) {
#pragma unroll
      for (int ns = 0; ns < 4; ns++) {
        int n = n0 + wn + ns * 16 + l15;
#pragma unroll
        for (int r = 0; r < 4; r++) {
          int m = m0 + wm + ms * 16 + quad * 4 + r;
          float s0 = acc0[ms][ns][r];
          float s1 = acc1[ms][ns][r];
          if (masked) {
            float w = maskb[(size_t)m * HW_ + n];   // one load, two uses
            s0 *= w; s1 *= w;
          }
          rm0[ns] = fmaxf(rm0[ns], s0);
          rm1[ns] = fmaxf(rm1[ns], s1);
        }
      }
    }
  }

  // reduce across quads (same column, different m rows)
#pragma unroll
  for (int ns = 0; ns < 4; ns++) {
    float v = rm0[ns];
    v = fmaxf(v, __shfl_xor(v, 16, 64));
    v = fmaxf(v, __shfl_xor(v, 32, 64));
    rm0[ns] = v;
    float u = rm1[ns];
    u = fmaxf(u, __shfl_xor(u, 16, 64));
    u = fmaxf(u, __shfl_xor(u, 32, 64));
    rm1[ns] = u;
  }
  if (lane < 16) {
#pragma unroll
    for (int ns = 0; ns < 4; ns++) {
      red[(wave & 1) * BN + wn + ns * 16 + l15]           = rm0[ns];
      red[2 * BN + (wave & 1) * BN + wn + ns * 16 + l15]  = rm1[ns];
    }
  }
  __syncthreads();
  if (t < BN) {
    float vv0 = fmaxf(red[t], red[BN + t]);
    float vv1 = fmaxf(red[2 * BN + t], red[3 * BN + t]);
    pmax[(((size_t)mc * B_ + b) * 4 + 2 * gp)     * HW_ + n0 + t] = vv0;
    pmax[(((size_t)mc * B_ + b) * 4 + 2 * gp + 1) * HW_ + n0 + t] = vv1;
  }
}

// max over m-chunks -> out channels 0..3
__global__ void fine_combine(const float* __restrict__ pmax, float* __restrict__ out) {
  int i = blockIdx.x * 256 + threadIdx.x;   // over B_*4*HW_
  if (i >= B_ * 4 * HW_) return;
  int n = i % HW_;
  int g = (i / HW_) % 4;
  int b = i / (HW_ * 4);
  float v = -3.4e38f;
#pragma unroll
  for (int mc = 0; mc < MCHUNKS; mc++)
    v = fmaxf(v, pmax[(((size_t)mc * B_ + b) * 4 + g) * HW_ + n]);
  out[((size_t)b * 10 + g) * HW_ + n] = v;
}

extern "C" void kernel_launch(void* const* d_in, const int* in_sizes, int n_in,
                              void* d_out, int out_size, void* d_ws, size_t ws_size,
                              hipStream_t stream) {
  const float* key  = (const float*)d_in[0];
  const float* sds  = (const float*)d_in[1];
  const float* gbg  = (const float*)d_in[2];
  const float* gfg  = (const float*)d_in[3];
  const float* lbg  = (const float*)d_in[4];
  const float* lfg  = (const float*)d_in[5];
  const float* obg  = (const float*)d_in[6];
  const float* ofg  = (const float*)d_in[7];
  const float* sbg  = (const float*)d_in[8];
  const float* sfg  = (const float*)d_in[9];
  const float* lobg = (const float*)d_in[10];
  const float* lofg = (const float*)d_in[11];
  float* out = (float*)d_out;

  unsigned short* keyT  = (unsigned short*)d_ws;               // 18.9 MB
  unsigned short* banks = keyT + (size_t)B_ * HW_ * C_;        // +75.5 MB
  float* pmax = (float*)(banks + (size_t)4 * B_ * HW_ * C_);   // +1.77 MB

  zero_out<<<(out_size + 255) / 256, 256, 0, stream>>>(out, out_size);
  convert_banks<<<dim3((B_ * HW_ * C_) / (4 * 256), 4), 256, 0, stream>>>(gbg, gfg, lbg, lfg, banks);
  transpose_coarse<<<dim3(HW_ / 32, C_ / 32, B_), dim3(32, 8), 0, stream>>>(
      key, obg, ofg, sbg, sfg, lobg, lofg, keyT, out);
  fine_kernel<<<dim3(NT_ * MCHUNKS, 2, B_), 256, 0, stream>>>(keyT, banks, sds, pmax);
  fine_combine<<<(B_ * 4 * HW_ + 255) / 256, 256, 0, stream>>>(pmax, out);
}